// Round 2
// baseline (728.827 us; speedup 1.0000x reference)
//
#include <hip/hip_runtime.h>
#include <hip/hip_bf16.h>

// out[i] = 10 * min_j ||x_i - y_j||, x: 8192x96 f32, y: 65536x96 f32.
// sq = x2[i] + (y2[j] - 2*x.y): bf16 MFMA computes (y2 - 2*x.y) by pre-scaling
// train by -2 (exact in bf16) and preloading y2 as the MFMA C operand.
// Train rows = MFMA M dim -> row-min folds inside each lane's accumulator.

typedef __attribute__((ext_vector_type(8))) short bf16x8;
typedef __attribute__((ext_vector_type(4))) float f32x4;

#define NQ 8192
#define NT 65536
#define KD 96
#define QB 512            // queries per WG: 4 waves x 128
#define TSPLIT 128        // train chunks
#define TCHUNK (NT / TSPLIT)   // 512 rows per WG
#define TTILE 64          // train rows per LDS tile
#define TILES (TCHUNK / TTILE) // 8
#define FRAG_USH 512      // ushorts per (tt,kb) fragment block (64 lanes x 8)

static __device__ __forceinline__ ushort f2bf(float f) {
  unsigned u = __float_as_uint(f);
  return (ushort)((u + 0x7fffu + ((u >> 16) & 1u)) >> 16);
}
static __device__ __forceinline__ unsigned pk2(float a, float b) {
  return (unsigned)f2bf(a) | ((unsigned)f2bf(b) << 16);
}

// 64 rows per block, float4-coalesced; norms via LDS float atomics.
__global__ __launch_bounds__(256) void prep_kernel(
    const float* __restrict__ qf, const float* __restrict__ tf,
    ushort* __restrict__ qbf, ushort* __restrict__ tbf,
    float* __restrict__ x2, float* __restrict__ y2,
    float* __restrict__ outp)
{
  __shared__ float snrm[64];
  const int tid = threadIdx.x;
  const int b = blockIdx.x;
  const bool isq = b < (NQ / 64);
  const int rb = isq ? b : b - (NQ / 64);
  const float4* src = (const float4*)((isq ? qf : tf) + (size_t)rb * 64 * KD);
  uint2* dst = (uint2*)((isq ? qbf : tbf) + (size_t)rb * 64 * KD);
  const float scale = isq ? 1.0f : -2.0f;

  if (tid < 64) snrm[tid] = 0.0f;
  __syncthreads();
  #pragma unroll
  for (int it = 0; it < 6; ++it) {
    int d = it * 256 + tid;           // float4 index, 0..1535
    float4 v = src[d];
    float ss = v.x * v.x + v.y * v.y + v.z * v.z + v.w * v.w;
    atomicAdd(&snrm[d / 24], ss);
    uint2 p; p.x = pk2(v.x * scale, v.y * scale); p.y = pk2(v.z * scale, v.w * scale);
    dst[d] = p;
  }
  __syncthreads();
  if (tid < 64) {
    int row = rb * 64 + tid;
    if (isq) { x2[row] = snrm[tid]; outp[row] = __uint_as_float(0x7f800000u); }
    else     { y2[row] = snrm[tid]; }
  }
}

__global__ __launch_bounds__(256, 3) void min_dist_kernel(
    const ushort* __restrict__ qbf, const ushort* __restrict__ tbf,
    const float* __restrict__ x2, const float* __restrict__ y2,
    float* __restrict__ outp)
{
  // fragment-major A tile: [tt][kb] blocks of 64 lanes x 16B, double-buffered
  __shared__ __align__(16) ushort ldsA[2][TTILE * KD];   // 2 x 12 KB
  __shared__ __align__(16) float ldsY[2][TTILE];

  const int tid  = threadIdx.x;
  const int w    = tid >> 6;
  const int lane = tid & 63;
  const int quad = lane >> 4;
  const int n    = lane & 15;
  const int tsplit = blockIdx.x & (TSPLIT - 1);   // same chunk -> same XCD slot
  const int qblock = blockIdx.x / TSPLIT;
  const int qbase  = qblock * QB + w * 128;

  // B-operand (query) fragments: 8 col-tiles x 3 k-blocks, resident all kernel
  bf16x8 bq[8][3];
  #pragma unroll
  for (int ct = 0; ct < 8; ++ct) {
    const ushort* qp = qbf + (size_t)(qbase + ct * 16 + n) * KD + quad * 8;
    #pragma unroll
    for (int kb = 0; kb < 3; ++kb)
      bq[ct][kb] = *(const bf16x8*)(qp + kb * 32);
  }

  // staging maps: thread stages 3 x 16B chunks; LDS offsets lane-contiguous
  int goff[3], loff[3];
  #pragma unroll
  for (int it = 0; it < 3; ++it) {
    int o = it * 256 + tid;           // 16B chunk id 0..767
    int frag = o >> 6;                // tt*3+kb, wave-uniform
    int tt = frag / 3, kb = frag - tt * 3;
    int l = o & 63;
    goff[it] = (tt * 16 + (l & 15)) * KD + kb * 32 + (l >> 4) * 8;  // ushort
    loff[it] = o * 8;                                                // ushort
  }

  const float INF = __uint_as_float(0x7f800000u);
  float m[8];
  #pragma unroll
  for (int ct = 0; ct < 8; ++ct) m[ct] = INF;

  const int trow0 = tsplit * TCHUNK;

  // prefetch tile 0
  uint4 pre[3]; float preY = 0.0f;
  {
    const ushort* g = tbf + (size_t)trow0 * KD;
    #pragma unroll
    for (int it = 0; it < 3; ++it) pre[it] = *(const uint4*)(g + goff[it]);
    if (tid < TTILE) preY = y2[trow0 + tid];
  }
  #pragma unroll
  for (int it = 0; it < 3; ++it) *(uint4*)&ldsA[0][loff[it]] = pre[it];
  if (tid < TTILE) ldsY[0][tid] = preY;
  __syncthreads();

  int cur = 0;
  #pragma unroll 1
  for (int tile = 0; tile < TILES; ++tile) {
    const bool more = (tile + 1) < TILES;
    if (more) {
      const ushort* g = tbf + (size_t)(trow0 + (tile + 1) * TTILE) * KD;
      #pragma unroll
      for (int it = 0; it < 3; ++it) pre[it] = *(const uint4*)(g + goff[it]);
      if (tid < TTILE) preY = y2[trow0 + (tile + 1) * TTILE + tid];
    }

    #pragma unroll
    for (int tt = 0; tt < 4; ++tt) {
      const ushort* ap = &ldsA[cur][tt * 3 * FRAG_USH + lane * 8];
      bf16x8 a0 = *(const bf16x8*)(ap);
      bf16x8 a1 = *(const bf16x8*)(ap + FRAG_USH);
      bf16x8 a2 = *(const bf16x8*)(ap + 2 * FRAG_USH);
      f32x4 y2v = *(const f32x4*)&ldsY[cur][tt * 16 + quad * 4];
      #pragma unroll
      for (int ct = 0; ct < 8; ++ct) {
        f32x4 acc = __builtin_amdgcn_mfma_f32_16x16x32_bf16(a0, bq[ct][0], y2v, 0, 0, 0);
        acc = __builtin_amdgcn_mfma_f32_16x16x32_bf16(a1, bq[ct][1], acc, 0, 0, 0);
        acc = __builtin_amdgcn_mfma_f32_16x16x32_bf16(a2, bq[ct][2], acc, 0, 0, 0);
        m[ct] = fminf(fminf(fminf(acc[0], acc[1]), acc[2]), fminf(acc[3], m[ct]));
      }
    }

    if (more) {
      int nxt = cur ^ 1;
      #pragma unroll
      for (int it = 0; it < 3; ++it) *(uint4*)&ldsA[nxt][loff[it]] = pre[it];
      if (tid < TTILE) ldsY[nxt][tid] = preY;
      __syncthreads();
      cur = nxt;
    }
  }

  // fold across quads (lanes with equal n hold the same query columns)
  #pragma unroll
  for (int ct = 0; ct < 8; ++ct) {
    m[ct] = fminf(m[ct], __shfl_xor(m[ct], 16, 64));
    m[ct] = fminf(m[ct], __shfl_xor(m[ct], 32, 64));
  }
  if (quad == 0) {
    #pragma unroll
    for (int ct = 0; ct < 8; ++ct) {
      int q = qbase + ct * 16 + n;
      float sq = fmaxf(x2[q] + m[ct], 0.0f);
      float val = sqrtf(sq) * 10.0f;
      atomicMin((unsigned int*)&outp[q], __float_as_uint(val));
    }
  }
}

extern "C" void kernel_launch(void* const* d_in, const int* in_sizes, int n_in,
                              void* d_out, int out_size, void* d_ws, size_t ws_size,
                              hipStream_t stream) {
  const float* qf = (const float*)d_in[0];   // mutation_dist 8192x96
  const float* tf = (const float*)d_in[1];   // train_data   65536x96
  float* outp = (float*)d_out;               // 8192 f32

  ushort* qbf = (ushort*)d_ws;                // 8192*96 bf16
  ushort* tbf = qbf + (size_t)NQ * KD;        // 65536*96 bf16, pre-scaled -2
  float* x2 = (float*)(tbf + (size_t)NT * KD);
  float* y2 = x2 + NQ;

  prep_kernel<<<(NQ + NT) / 64, 256, 0, stream>>>(qf, tf, qbf, tbf, x2, y2, outp);
  min_dist_kernel<<<(NQ / QB) * TSPLIT, 256, 0, stream>>>(qbf, tbf, x2, y2, outp);
}

// Round 3
// 228.859 us; speedup vs baseline: 3.1846x; 3.1846x over previous
//
#include <hip/hip_runtime.h>
#include <hip/hip_bf16.h>

// out[i] = 10 * min_j ||x_i - y_j||, x: 8192x96 f32, y: 65536x96 f32.
// sq = x2[i] + (y2[j] - 2*x.y): bf16 MFMA computes (y2 - 2*x.y) by pre-scaling
// train by -2 (exact in bf16) and preloading y2 as the MFMA C operand.
// Train rows = MFMA M dim -> row-min folds inside each lane's accumulator.
// R3: ct=4 (48-VGPR B-frags, no spill) + fragment-major conflict-free LDS +
// single-barrier double-buffered tile pipeline.

typedef __attribute__((ext_vector_type(8))) short bf16x8;
typedef __attribute__((ext_vector_type(4))) float f32x4;

#define NQ 8192
#define NT 65536
#define KD 96
#define QB 256            // queries per WG: 4 waves x 64
#define TSPLIT 32         // train chunks; tsplit t -> XCD t%8 (L2-resident)
#define TCHUNK (NT / TSPLIT)   // 2048 rows per WG
#define TTILE 64          // train rows per LDS tile
#define TILES (TCHUNK / TTILE) // 32
#define FRAG_USH 512      // ushorts per (tt,kb) fragment block (64 lanes x 8)

static __device__ __forceinline__ ushort f2bf(float f) {
  unsigned u = __float_as_uint(f);
  return (ushort)((u + 0x7fffu + ((u >> 16) & 1u)) >> 16);
}
static __device__ __forceinline__ unsigned pk2(float a, float b) {
  return (unsigned)f2bf(a) | ((unsigned)f2bf(b) << 16);
}

// 64 rows per block, float4-coalesced; row norms via LDS float atomics.
__global__ __launch_bounds__(256) void prep_kernel(
    const float* __restrict__ qf, const float* __restrict__ tf,
    ushort* __restrict__ qbf, ushort* __restrict__ tbf,
    float* __restrict__ x2, float* __restrict__ y2,
    float* __restrict__ outp)
{
  __shared__ float snrm[64];
  const int tid = threadIdx.x;
  const int b = blockIdx.x;
  const bool isq = b < (NQ / 64);
  const int rb = isq ? b : b - (NQ / 64);
  const float4* src = (const float4*)((isq ? qf : tf) + (size_t)rb * 64 * KD);
  uint2* dst = (uint2*)((isq ? qbf : tbf) + (size_t)rb * 64 * KD);
  const float scale = isq ? 1.0f : -2.0f;

  if (tid < 64) snrm[tid] = 0.0f;
  __syncthreads();
  #pragma unroll
  for (int it = 0; it < 6; ++it) {
    int d = it * 256 + tid;           // float4 index, 0..1535
    float4 v = src[d];
    float ss = v.x * v.x + v.y * v.y + v.z * v.z + v.w * v.w;
    atomicAdd(&snrm[d / 24], ss);
    uint2 p; p.x = pk2(v.x * scale, v.y * scale); p.y = pk2(v.z * scale, v.w * scale);
    dst[d] = p;
  }
  __syncthreads();
  if (tid < 64) {
    int row = rb * 64 + tid;
    if (isq) { x2[row] = snrm[tid]; outp[row] = __uint_as_float(0x7f800000u); }
    else     { y2[row] = snrm[tid]; }
  }
}

__global__ __launch_bounds__(256, 3) void min_dist_kernel(
    const ushort* __restrict__ qbf, const ushort* __restrict__ tbf,
    const float* __restrict__ x2, const float* __restrict__ y2,
    float* __restrict__ outp)
{
  // fragment-major A tile: [tt][kb] blocks of 64 lanes x 16B, double-buffered
  __shared__ __align__(16) ushort ldsA[2][TTILE * KD];   // 2 x 12 KB
  __shared__ __align__(16) float ldsY[2][TTILE];

  const int tid  = threadIdx.x;
  const int w    = tid >> 6;
  const int lane = tid & 63;
  const int quad = lane >> 4;
  const int n    = lane & 15;
  const int tsplit = blockIdx.x & (TSPLIT - 1);   // -> XCD tsplit%8
  const int qblock = blockIdx.x / TSPLIT;
  const int qbase  = qblock * QB + w * 64;

  // B-operand (query) fragments: 4 col-tiles x 3 k-blocks = 48 VGPRs, resident
  bf16x8 bq[4][3];
  #pragma unroll
  for (int ct = 0; ct < 4; ++ct) {
    const ushort* qp = qbf + (size_t)(qbase + ct * 16 + n) * KD + quad * 8;
    #pragma unroll
    for (int kb = 0; kb < 3; ++kb)
      bq[ct][kb] = *(const bf16x8*)(qp + kb * 32);
  }

  // staging map: thread stages 3 x 16B chunks, LDS lane-contiguous
  int goff[3], loff[3];
  #pragma unroll
  for (int it = 0; it < 3; ++it) {
    int o = it * 256 + tid;           // 16B chunk id 0..767
    int frag = o >> 6;                // tt*3+kb (wave-uniform)
    int tt = frag / 3, kb = frag - tt * 3;
    int l = o & 63;
    goff[it] = (tt * 16 + (l & 15)) * KD + kb * 32 + (l >> 4) * 8;  // ushort
    loff[it] = o * 8;                                                // ushort
  }

  const float INF = __uint_as_float(0x7f800000u);
  float m0 = INF, m1 = INF, m2 = INF, m3 = INF;

  const int trow0 = tsplit * TCHUNK;

  // prefetch tile 0
  uint4 pre[3]; float preY = 0.0f;
  {
    const ushort* g = tbf + (size_t)trow0 * KD;
    #pragma unroll
    for (int it = 0; it < 3; ++it) pre[it] = *(const uint4*)(g + goff[it]);
    if (tid < TTILE) preY = y2[trow0 + tid];
  }
  #pragma unroll
  for (int it = 0; it < 3; ++it) *(uint4*)&ldsA[0][loff[it]] = pre[it];
  if (tid < TTILE) ldsY[0][tid] = preY;
  __syncthreads();

  int cur = 0;
  #pragma unroll 1
  for (int tile = 0; tile < TILES; ++tile) {
    const bool more = (tile + 1) < TILES;
    if (more) {
      const ushort* g = tbf + (size_t)(trow0 + (tile + 1) * TTILE) * KD;
      #pragma unroll
      for (int it = 0; it < 3; ++it) pre[it] = *(const uint4*)(g + goff[it]);
      if (tid < TTILE) preY = y2[trow0 + (tile + 1) * TTILE + tid];
    }

    #pragma unroll
    for (int tt = 0; tt < 4; ++tt) {
      const ushort* ap = &ldsA[cur][tt * 3 * FRAG_USH + lane * 8];
      bf16x8 a0 = *(const bf16x8*)(ap);
      bf16x8 a1 = *(const bf16x8*)(ap + FRAG_USH);
      bf16x8 a2 = *(const bf16x8*)(ap + 2 * FRAG_USH);
      f32x4 y2v = *(const f32x4*)&ldsY[cur][tt * 16 + quad * 4];
      #pragma unroll
      for (int ct = 0; ct < 4; ++ct) {
        f32x4 acc = __builtin_amdgcn_mfma_f32_16x16x32_bf16(a0, bq[ct][0], y2v, 0, 0, 0);
        acc = __builtin_amdgcn_mfma_f32_16x16x32_bf16(a1, bq[ct][1], acc, 0, 0, 0);
        acc = __builtin_amdgcn_mfma_f32_16x16x32_bf16(a2, bq[ct][2], acc, 0, 0, 0);
        float t = fminf(fminf(acc[0], acc[1]), fminf(acc[2], acc[3]));
        if (ct == 0) m0 = fminf(m0, t);
        else if (ct == 1) m1 = fminf(m1, t);
        else if (ct == 2) m2 = fminf(m2, t);
        else m3 = fminf(m3, t);
      }
    }

    if (more) {
      int nxt = cur ^ 1;
      #pragma unroll
      for (int it = 0; it < 3; ++it) *(uint4*)&ldsA[nxt][loff[it]] = pre[it];
      if (tid < TTILE) ldsY[nxt][tid] = preY;
      __syncthreads();
      cur = nxt;
    }
  }

  // fold across quads (lanes with equal n hold the same query columns)
  float m[4] = {m0, m1, m2, m3};
  #pragma unroll
  for (int ct = 0; ct < 4; ++ct) {
    m[ct] = fminf(m[ct], __shfl_xor(m[ct], 16, 64));
    m[ct] = fminf(m[ct], __shfl_xor(m[ct], 32, 64));
  }
  if (quad == 0) {
    #pragma unroll
    for (int ct = 0; ct < 4; ++ct) {
      int q = qbase + ct * 16 + n;
      float sq = fmaxf(x2[q] + m[ct], 0.0f);
      float val = sqrtf(sq) * 10.0f;
      atomicMin((unsigned int*)&outp[q], __float_as_uint(val));
    }
  }
}

extern "C" void kernel_launch(void* const* d_in, const int* in_sizes, int n_in,
                              void* d_out, int out_size, void* d_ws, size_t ws_size,
                              hipStream_t stream) {
  const float* qf = (const float*)d_in[0];   // mutation_dist 8192x96
  const float* tf = (const float*)d_in[1];   // train_data   65536x96
  float* outp = (float*)d_out;               // 8192 f32

  ushort* qbf = (ushort*)d_ws;                // 8192*96 bf16
  ushort* tbf = qbf + (size_t)NQ * KD;        // 65536*96 bf16, pre-scaled -2
  float* x2 = (float*)(tbf + (size_t)NT * KD);
  float* y2 = x2 + NQ;

  prep_kernel<<<(NQ + NT) / 64, 256, 0, stream>>>(qf, tf, qbf, tbf, x2, y2, outp);
  min_dist_kernel<<<(NQ / QB) * TSPLIT, 256, 0, stream>>>(qbf, tbf, x2, y2, outp);
}

// Round 4
// 189.936 us; speedup vs baseline: 3.8372x; 1.2049x over previous
//
#include <hip/hip_runtime.h>
#include <hip/hip_bf16.h>

// out[i] = 10 * min_j ||x_i - y_j||, x: 8192x96 f32, y: 65536x96 f32.
// sq = x2[i] + (y2[j] - 2*x.y): bf16 MFMA computes (y2 - 2*x.y) by pre-scaling
// train by -2 (exact in bf16) and preloading y2 as the MFMA C operand.
// R4: NO LDS, NO barriers in the main kernel. Queries live in 48 VGPRs
// (B operand); train A-frags are loaded straight from global (row-major
// fragment reads are 16B-aligned), served by L1 (4-wave reuse in WG) and
// XCD-pinned L2 (32-WG reuse per chunk). One-deep register prefetch gives
// the fine-grained-vmcnt MFMA<->VMEM overlap a barriered K-loop can't.

typedef __attribute__((ext_vector_type(8))) short bf16x8;
typedef __attribute__((ext_vector_type(4))) float f32x4;

#define NQ 8192
#define NT 65536
#define KD 96
#define QB 256            // queries per WG: 4 waves x 64
#define TSPLIT 32         // train chunks; chunk t -> XCD t%8 (L2-resident)
#define TCHUNK (NT / TSPLIT)   // 2048 rows per WG
#define NTT (TCHUNK / 16)      // 128 MFMA row-tiles per WG

static __device__ __forceinline__ ushort f2bf(float f) {
  unsigned u = __float_as_uint(f);
  return (ushort)((u + 0x7fffu + ((u >> 16) & 1u)) >> 16);
}
static __device__ __forceinline__ unsigned pk2(float a, float b) {
  return (unsigned)f2bf(a) | ((unsigned)f2bf(b) << 16);
}

// 64 rows per block, float4-coalesced; row norms via LDS float atomics.
__global__ __launch_bounds__(256) void prep_kernel(
    const float* __restrict__ qf, const float* __restrict__ tf,
    ushort* __restrict__ qbf, ushort* __restrict__ tbf,
    float* __restrict__ x2, float* __restrict__ y2,
    float* __restrict__ outp)
{
  __shared__ float snrm[64];
  const int tid = threadIdx.x;
  const int b = blockIdx.x;
  const bool isq = b < (NQ / 64);
  const int rb = isq ? b : b - (NQ / 64);
  const float4* src = (const float4*)((isq ? qf : tf) + (size_t)rb * 64 * KD);
  uint2* dst = (uint2*)((isq ? qbf : tbf) + (size_t)rb * 64 * KD);
  const float scale = isq ? 1.0f : -2.0f;

  if (tid < 64) snrm[tid] = 0.0f;
  __syncthreads();
  #pragma unroll
  for (int it = 0; it < 6; ++it) {
    int d = it * 256 + tid;           // float4 index, 0..1535
    float4 v = src[d];
    float ss = v.x * v.x + v.y * v.y + v.z * v.z + v.w * v.w;
    atomicAdd(&snrm[d / 24], ss);
    uint2 p; p.x = pk2(v.x * scale, v.y * scale); p.y = pk2(v.z * scale, v.w * scale);
    dst[d] = p;
  }
  __syncthreads();
  if (tid < 64) {
    int row = rb * 64 + tid;
    if (isq) { x2[row] = snrm[tid]; outp[row] = __uint_as_float(0x7f800000u); }
    else     { y2[row] = snrm[tid]; }
  }
}

__global__ __launch_bounds__(256, 4) void min_dist_kernel(
    const ushort* __restrict__ qbf, const ushort* __restrict__ tbf,
    const float* __restrict__ x2, const float* __restrict__ y2,
    float* __restrict__ outp)
{
  const int tid  = threadIdx.x;
  const int w    = tid >> 6;
  const int lane = tid & 63;
  const int quad = lane >> 4;
  const int n    = lane & 15;
  const int tsplit = blockIdx.x & (TSPLIT - 1);   // -> XCD tsplit%8
  const int qblock = blockIdx.x / TSPLIT;
  const int qbase  = qblock * QB + w * 64;

  // B-operand (query) fragments: 4 col-tiles x 3 k-blocks = 48 VGPRs, resident
  bf16x8 bq[4][3];
  #pragma unroll
  for (int ct = 0; ct < 4; ++ct) {
    const ushort* qp = qbf + (size_t)(qbase + ct * 16 + n) * KD + quad * 8;
    #pragma unroll
    for (int kb = 0; kb < 3; ++kb)
      bq[ct][kb] = *(const bf16x8*)(qp + kb * 32);
  }

  const float INF = __uint_as_float(0x7f800000u);
  float m0 = INF, m1 = INF, m2 = INF, m3 = INF;

  const int trow0 = tsplit * TCHUNK;
  // lane-fixed fragment bases; advance 16 rows (= 16*KD ushorts) per tt
  const ushort* tp = tbf + (size_t)(trow0 + n) * KD + quad * 8;
  const float*  yp = y2 + trow0 + quad * 4;

  // prefetch tt=0
  bf16x8 a0 = *(const bf16x8*)(tp);
  bf16x8 a1 = *(const bf16x8*)(tp + 32);
  bf16x8 a2 = *(const bf16x8*)(tp + 64);
  f32x4  yv = *(const f32x4*)(yp);

  #pragma unroll 1
  for (int t = 0; t < NTT; ++t) {
    // prefetch tt=t+1 (last iter re-loads t: L1-hit, keeps loop branch-free)
    const int tn = (t + 1 < NTT) ? (t + 1) : t;
    const ushort* tpn = tp + tn * (16 * KD);
    bf16x8 na0 = *(const bf16x8*)(tpn);
    bf16x8 na1 = *(const bf16x8*)(tpn + 32);
    bf16x8 na2 = *(const bf16x8*)(tpn + 64);
    f32x4  nyv = *(const f32x4*)(yp + tn * 16);

    f32x4 acc;
    acc = __builtin_amdgcn_mfma_f32_16x16x32_bf16(a0, bq[0][0], yv, 0, 0, 0);
    acc = __builtin_amdgcn_mfma_f32_16x16x32_bf16(a1, bq[0][1], acc, 0, 0, 0);
    acc = __builtin_amdgcn_mfma_f32_16x16x32_bf16(a2, bq[0][2], acc, 0, 0, 0);
    m0 = fminf(fminf(fminf(acc[0], acc[1]), fminf(acc[2], acc[3])), m0);

    acc = __builtin_amdgcn_mfma_f32_16x16x32_bf16(a0, bq[1][0], yv, 0, 0, 0);
    acc = __builtin_amdgcn_mfma_f32_16x16x32_bf16(a1, bq[1][1], acc, 0, 0, 0);
    acc = __builtin_amdgcn_mfma_f32_16x16x32_bf16(a2, bq[1][2], acc, 0, 0, 0);
    m1 = fminf(fminf(fminf(acc[0], acc[1]), fminf(acc[2], acc[3])), m1);

    acc = __builtin_amdgcn_mfma_f32_16x16x32_bf16(a0, bq[2][0], yv, 0, 0, 0);
    acc = __builtin_amdgcn_mfma_f32_16x16x32_bf16(a1, bq[2][1], acc, 0, 0, 0);
    acc = __builtin_amdgcn_mfma_f32_16x16x32_bf16(a2, bq[2][2], acc, 0, 0, 0);
    m2 = fminf(fminf(fminf(acc[0], acc[1]), fminf(acc[2], acc[3])), m2);

    acc = __builtin_amdgcn_mfma_f32_16x16x32_bf16(a0, bq[3][0], yv, 0, 0, 0);
    acc = __builtin_amdgcn_mfma_f32_16x16x32_bf16(a1, bq[3][1], acc, 0, 0, 0);
    acc = __builtin_amdgcn_mfma_f32_16x16x32_bf16(a2, bq[3][2], acc, 0, 0, 0);
    m3 = fminf(fminf(fminf(acc[0], acc[1]), fminf(acc[2], acc[3])), m3);

    a0 = na0; a1 = na1; a2 = na2; yv = nyv;
  }

  // fold across quads (lanes with equal n hold the same query columns)
  float m[4] = {m0, m1, m2, m3};
  #pragma unroll
  for (int ct = 0; ct < 4; ++ct) {
    m[ct] = fminf(m[ct], __shfl_xor(m[ct], 16, 64));
    m[ct] = fminf(m[ct], __shfl_xor(m[ct], 32, 64));
  }
  if (quad == 0) {
    #pragma unroll
    for (int ct = 0; ct < 4; ++ct) {
      int q = qbase + ct * 16 + n;
      float sq = fmaxf(x2[q] + m[ct], 0.0f);
      float val = sqrtf(sq) * 10.0f;
      atomicMin((unsigned int*)&outp[q], __float_as_uint(val));
    }
  }
}

extern "C" void kernel_launch(void* const* d_in, const int* in_sizes, int n_in,
                              void* d_out, int out_size, void* d_ws, size_t ws_size,
                              hipStream_t stream) {
  const float* qf = (const float*)d_in[0];   // mutation_dist 8192x96
  const float* tf = (const float*)d_in[1];   // train_data   65536x96
  float* outp = (float*)d_out;               // 8192 f32

  ushort* qbf = (ushort*)d_ws;                // 8192*96 bf16
  ushort* tbf = qbf + (size_t)NQ * KD;        // 65536*96 bf16, pre-scaled -2
  float* x2 = (float*)(tbf + (size_t)NT * KD);
  float* y2 = x2 + NQ;

  prep_kernel<<<(NQ + NT) / 64, 256, 0, stream>>>(qf, tf, qbf, tbf, x2, y2, outp);
  min_dist_kernel<<<(NQ / QB) * TSPLIT, 256, 0, stream>>>(qbf, tbf, x2, y2, outp);
}